// Round 4
// baseline (74.731 us; speedup 1.0000x reference)
//
#include <hip/hip_runtime.h>

// ---------------------------------------------------------------------------
// LearnedBoardEncoder, factorized.
//
// piece_ids in [0,7), color_ids in [0,3), square in [0,64): the per-square
// token LN(W[c] @ piece_table[p] + b[c] + square_table[s]) takes only
// 7*3*64 = 1344 distinct values; special tokens take 2+16+9 = 27. Precompute
// all 1371 layernormed rows into a workspace table, then the op is a pure
// gather (write-bound: 281 MB out @ ~6.9 TB/s ≈ 41 us floor).
//
// R4: table build fused into ONE kernel (22 blocks: 21 matvec+LN-64-squares
// blocks + 1 special-rows block); gather keeps block-per-board structure but
// reverts NT stores to plain stores (fillBuffer evidence: plain stores reach
// 6.9 TB/s; NT bought nothing in R3).
// ---------------------------------------------------------------------------

#define DIM 256
#define NPT 7
#define NCOL 3
#define NROWS_SQ (NPT * NCOL * 64)   // 1344
#define ROW_TURN 1344                // 2 rows
#define ROW_CASTLE 1346              // 16 rows
#define ROW_EP 1362                  // 9 rows
#define NROWS_TOT 1371
#define EPSV 1e-5f

__device__ __forceinline__ float4 ln4(float4 x, float4 g, float4 bb) {
    float s = x.x + x.y + x.z + x.w;
    #pragma unroll
    for (int m = 1; m < 64; m <<= 1) s += __shfl_xor(s, m, 64);
    float mu = s * (1.0f / DIM);
    float dx = x.x - mu, dy = x.y - mu, dz = x.z - mu, dw = x.w - mu;
    float v = dx * dx + dy * dy + dz * dz + dw * dw;
    #pragma unroll
    for (int m = 1; m < 64; m <<= 1) v += __shfl_xor(v, m, 64);
    float inv = rsqrtf(v * (1.0f / DIM) + EPSV);
    return make_float4(dx * inv * g.x + bb.x,
                       dy * inv * g.y + bb.y,
                       dz * inv * g.z + bb.z,
                       dw * inv * g.w + bb.w);
}

// ---- Kernel A: build the whole 1371-row layernormed table in one launch.
// Blocks 0..20: (p,c) pair — matvec proj into LDS, then LN 64 square rows.
// Block 21: LN the 27 special rows (turn/castling/ep).
__global__ __launch_bounds__(256) void table_kernel(
        const float* __restrict__ piece_table,
        const float* __restrict__ W,
        const float* __restrict__ bvec,
        const float* __restrict__ square_table,
        const float* __restrict__ turn_table,
        const float* __restrict__ castling_table,
        const float* __restrict__ ep_table,
        const float* __restrict__ gamma,
        const float* __restrict__ beta,
        float* __restrict__ table) {
    int e = blockIdx.x;
    int tid = threadIdx.x;
    int wave = tid >> 6, lane = tid & 63;
    float4 g  = ((const float4*)gamma)[lane];
    float4 bb = ((const float4*)beta)[lane];

    if (e < NPT * NCOL) {
        int p = e / NCOL, c = e % NCOL;
        __shared__ float pt[DIM];
        __shared__ float projs[DIM];
        pt[tid] = piece_table[p * DIM + tid];
        __syncthreads();
        const float4* w4 = (const float4*)(W + (size_t)c * DIM * DIM + (size_t)tid * DIM);
        float acc = bvec[c * DIM + tid];
        #pragma unroll 8
        for (int k = 0; k < DIM / 4; ++k) {
            float4 w = w4[k];
            acc += w.x * pt[k * 4 + 0] + w.y * pt[k * 4 + 1]
                 + w.z * pt[k * 4 + 2] + w.w * pt[k * 4 + 3];
        }
        projs[tid] = acc;
        __syncthreads();

        float4 a = ((const float4*)projs)[lane];
        float* tbase = table + (size_t)(p * (NCOL * 64) + c * 64) * DIM;
        for (int s = wave; s < 64; s += 4) {
            float4 q = ((const float4*)(square_table + s * DIM))[lane];
            float4 x = make_float4(a.x + q.x, a.y + q.y, a.z + q.z, a.w + q.w);
            ((float4*)(tbase + (size_t)s * DIM))[lane] = ln4(x, g, bb);
        }
    } else {
        // 27 special rows
        for (int w = wave; w < 27; w += 4) {
            float4 x;
            if (w < 2) {
                x = ((const float4*)(turn_table + w * DIM))[lane];
            } else if (w < 18) {
                x = ((const float4*)(castling_table + (w - 2) * DIM))[lane];
            } else {
                x = ((const float4*)(ep_table + (w - 18) * DIM))[lane];
            }
            ((float4*)(table + (size_t)(ROW_TURN + w) * DIM))[lane] = ln4(x, g, bb);
        }
    }
}

// ---- Kernel B: gather, block-per-board.
// Phase 1: 67 row indices -> LDS (coalesced index loads).
// Phase 2: 4 waves copy 67 rows (1 KB each), plain float4 stores.
__global__ __launch_bounds__(256) void gather_kernel(
        const int* __restrict__ piece_ids,
        const int* __restrict__ color_ids,
        const int* __restrict__ turn,
        const int* __restrict__ castling,
        const int* __restrict__ ep_file,
        const float* __restrict__ table,
        float* __restrict__ out) {
    int b = blockIdx.x;
    __shared__ int rows[67];
    int tid = threadIdx.x;
    if (tid < 64) {
        int pid = piece_ids[b * 64 + tid];
        int cid = color_ids[b * 64 + tid];
        rows[3 + tid] = pid * (NCOL * 64) + cid * 64 + tid;
    } else if (tid == 64) {
        rows[0] = ROW_TURN + turn[b];
    } else if (tid == 65) {
        rows[1] = ROW_CASTLE + castling[b];
    } else if (tid == 66) {
        rows[2] = ROW_EP + ep_file[b];
    }
    __syncthreads();

    int wave = tid >> 6, lane = tid & 63;
    float4* outb = (float4*)(out + (size_t)b * 67 * DIM);
    #pragma unroll 4
    for (int t = wave; t < 67; t += 4) {
        float4 v = ((const float4*)(table + (size_t)rows[t] * DIM))[lane];
        outb[t * (DIM / 4) + lane] = v;
    }
}

extern "C" void kernel_launch(void* const* d_in, const int* in_sizes, int n_in,
                              void* d_out, int out_size, void* d_ws, size_t ws_size,
                              hipStream_t stream) {
    const int*   piece_ids      = (const int*)d_in[0];
    const int*   color_ids      = (const int*)d_in[1];
    const int*   turn           = (const int*)d_in[2];
    const int*   castling       = (const int*)d_in[3];
    const int*   ep_file        = (const int*)d_in[4];
    const float* piece_table    = (const float*)d_in[5];
    const float* W              = (const float*)d_in[6];
    const float* bvec           = (const float*)d_in[7];
    const float* square_table   = (const float*)d_in[8];
    const float* turn_table     = (const float*)d_in[9];
    const float* castling_table = (const float*)d_in[10];
    const float* ep_table       = (const float*)d_in[11];
    const float* gamma          = (const float*)d_in[12];
    const float* beta           = (const float*)d_in[13];
    float* out = (float*)d_out;

    int B = in_sizes[0] / 64;
    float* table = (float*)d_ws;                 // 1371 * 256 floats

    table_kernel<<<NPT * NCOL + 1, 256, 0, stream>>>(
        piece_table, W, bvec, square_table, turn_table, castling_table,
        ep_table, gamma, beta, table);
    gather_kernel<<<B, 256, 0, stream>>>(
        piece_ids, color_ids, turn, castling, ep_file, table, out);
}

// Round 5
// 71.071 us; speedup vs baseline: 1.0515x; 1.0515x over previous
//
#include <hip/hip_runtime.h>

// ---------------------------------------------------------------------------
// LearnedBoardEncoder, factorized.
//
// piece_ids in [0,7), color_ids in [0,3), square in [0,64): the per-square
// token LN(W[c] @ piece_table[p] + b[c] + square_table[s]) takes only
// 7*3*64 = 1344 distinct values; special tokens take 2+16+9 = 27. Precompute
// all 1371 layernormed rows (ws table), then the op is a pure gather
// (write-bound: 281 MB out @ ~7 TB/s fill-rate ≈ 41 us floor).
//
// R5: prologue kernels identical to R1 (best measured). Gather restructured
// for dispatch-grain + MLP: 1024-thread blocks, 4 rows per wave, batched
// independent load/store chains, plain float4 stores.
// ---------------------------------------------------------------------------

#define DIM 256
#define NPT 7
#define NCOL 3
#define NROWS_SQ (NPT * NCOL * 64)   // 1344
#define ROW_TURN 1344                // 2 rows
#define ROW_CASTLE 1346              // 16 rows
#define ROW_EP 1362                  // 9 rows
#define NROWS_TOT 1371
#define EPSV 1e-5f
#define ROWS_PER_WAVE 4
#define GATHER_BLOCK 1024
#define ROWS_PER_BLOCK ((GATHER_BLOCK / 64) * ROWS_PER_WAVE)   // 64

// ---- Kernel A: proj[p*3+c][d] = b[c][d] + sum_k W[c][d][k] * piece_table[p][k]
__global__ void proj_kernel(const float* __restrict__ piece_table,
                            const float* __restrict__ W,
                            const float* __restrict__ bvec,
                            float* __restrict__ proj) {
    int e = blockIdx.x;              // 0..20  (p*3 + c)
    int p = e / NCOL, c = e % NCOL;
    int d = threadIdx.x;             // 0..255 (output element o)
    __shared__ float pt[DIM];
    pt[d] = piece_table[p * DIM + d];
    __syncthreads();
    const float4* w4 = (const float4*)(W + (size_t)c * DIM * DIM + (size_t)d * DIM);
    float acc = bvec[c * DIM + d];
    #pragma unroll 8
    for (int k = 0; k < DIM / 4; ++k) {
        float4 w = w4[k];
        acc += w.x * pt[k * 4 + 0] + w.y * pt[k * 4 + 1]
             + w.z * pt[k * 4 + 2] + w.w * pt[k * 4 + 3];
    }
    proj[e * DIM + d] = acc;
}

// ---- Kernel B: layernorm each of the 1371 distinct rows into `table`.
// One wave (64 lanes) per row; each lane owns 4 consecutive floats.
__global__ void ln_table_kernel(const float* __restrict__ proj,
                                const float* __restrict__ square_table,
                                const float* __restrict__ turn_table,
                                const float* __restrict__ castling_table,
                                const float* __restrict__ ep_table,
                                const float* __restrict__ gamma,
                                const float* __restrict__ beta,
                                float* __restrict__ table) {
    int w = blockIdx.x * 4 + (threadIdx.x >> 6);
    int lane = threadIdx.x & 63;
    if (w >= NROWS_TOT) return;

    float4 x;
    if (w < NROWS_SQ) {
        int p = w / 192;
        int rem = w - p * 192;
        int c = rem >> 6;
        int s = rem & 63;
        float4 a = ((const float4*)(proj + (p * NCOL + c) * DIM))[lane];
        float4 q = ((const float4*)(square_table + s * DIM))[lane];
        x = make_float4(a.x + q.x, a.y + q.y, a.z + q.z, a.w + q.w);
    } else if (w < ROW_CASTLE) {
        x = ((const float4*)(turn_table + (w - ROW_TURN) * DIM))[lane];
    } else if (w < ROW_EP) {
        x = ((const float4*)(castling_table + (w - ROW_CASTLE) * DIM))[lane];
    } else {
        x = ((const float4*)(ep_table + (w - ROW_EP) * DIM))[lane];
    }

    float s = x.x + x.y + x.z + x.w;
    #pragma unroll
    for (int m = 1; m < 64; m <<= 1) s += __shfl_xor(s, m, 64);
    float mu = s * (1.0f / DIM);

    float dx = x.x - mu, dy = x.y - mu, dz = x.z - mu, dw = x.w - mu;
    float v = dx * dx + dy * dy + dz * dz + dw * dw;
    #pragma unroll
    for (int m = 1; m < 64; m <<= 1) v += __shfl_xor(v, m, 64);
    float inv = rsqrtf(v * (1.0f / DIM) + EPSV);

    float4 g = ((const float4*)gamma)[lane];
    float4 bb = ((const float4*)beta)[lane];
    float4 y = make_float4(dx * inv * g.x + bb.x,
                           dy * inv * g.y + bb.y,
                           dz * inv * g.z + bb.z,
                           dw * inv * g.w + bb.w);
    ((float4*)(table + (size_t)w * DIM))[lane] = y;
}

// ---- Kernel C: gather. 1024-thread blocks; each wave copies 4 rows.
// Index chains, table loads, and stores batched for MLP; all-register
// (statically indexed after unroll).
__global__ __launch_bounds__(GATHER_BLOCK) void gather_kernel(
        const int* __restrict__ piece_ids,
        const int* __restrict__ color_ids,
        const int* __restrict__ turn,
        const int* __restrict__ castling,
        const int* __restrict__ ep_file,
        const float* __restrict__ table,
        float* __restrict__ out,
        int nrows) {
    int gw = blockIdx.x * (GATHER_BLOCK / 64) + (threadIdx.x >> 6);
    int lane = threadIdx.x & 63;
    int r0 = gw * ROWS_PER_WAVE;
    if (r0 >= nrows) return;
    bool full = (r0 + ROWS_PER_WAVE) <= nrows;

    int rowidx[ROWS_PER_WAVE];
    #pragma unroll
    for (int i = 0; i < ROWS_PER_WAVE; ++i) {
        int r = r0 + i;
        if (!full && r >= nrows) r = r0;     // tail: harmless duplicate
        int b = r / 67;
        int t = r - b * 67;
        int row;
        if (t >= 3) {
            int s = t - 3;
            int idx = b * 64 + s;
            row = piece_ids[idx] * (NCOL * 64) + color_ids[idx] * 64 + s;
        } else if (t == 0) {
            row = ROW_TURN + turn[b];
        } else if (t == 1) {
            row = ROW_CASTLE + castling[b];
        } else {
            row = ROW_EP + ep_file[b];
        }
        rowidx[i] = row;
    }

    float4 v[ROWS_PER_WAVE];
    #pragma unroll
    for (int i = 0; i < ROWS_PER_WAVE; ++i)
        v[i] = ((const float4*)table)[(size_t)rowidx[i] * (DIM / 4) + lane];

    #pragma unroll
    for (int i = 0; i < ROWS_PER_WAVE; ++i) {
        int r = r0 + i;
        if (full || r < nrows)
            ((float4*)out)[(size_t)r * (DIM / 4) + lane] = v[i];
    }
}

extern "C" void kernel_launch(void* const* d_in, const int* in_sizes, int n_in,
                              void* d_out, int out_size, void* d_ws, size_t ws_size,
                              hipStream_t stream) {
    const int*   piece_ids      = (const int*)d_in[0];
    const int*   color_ids      = (const int*)d_in[1];
    const int*   turn           = (const int*)d_in[2];
    const int*   castling       = (const int*)d_in[3];
    const int*   ep_file        = (const int*)d_in[4];
    const float* piece_table    = (const float*)d_in[5];
    const float* W              = (const float*)d_in[6];
    const float* bvec           = (const float*)d_in[7];
    const float* square_table   = (const float*)d_in[8];
    const float* turn_table     = (const float*)d_in[9];
    const float* castling_table = (const float*)d_in[10];
    const float* ep_table       = (const float*)d_in[11];
    const float* gamma          = (const float*)d_in[12];
    const float* beta           = (const float*)d_in[13];
    float* out = (float*)d_out;

    int B = in_sizes[0] / 64;
    int nrows = B * 67;

    float* proj  = (float*)d_ws;                 // 21 * 256 floats
    float* table = proj + NPT * NCOL * DIM;      // 1371 * 256 floats

    proj_kernel<<<NPT * NCOL, 256, 0, stream>>>(piece_table, W, bvec, proj);
    ln_table_kernel<<<(NROWS_TOT + 3) / 4, 256, 0, stream>>>(
        proj, square_table, turn_table, castling_table, ep_table, gamma, beta, table);
    int grid = (nrows + ROWS_PER_BLOCK - 1) / ROWS_PER_BLOCK;
    gather_kernel<<<grid, GATHER_BLOCK, 0, stream>>>(
        piece_ids, color_ids, turn, castling, ep_file, table, out, nrows);
}

// Round 6
// 61.958 us; speedup vs baseline: 1.2062x; 1.1471x over previous
//
#include <hip/hip_runtime.h>

// ---------------------------------------------------------------------------
// LearnedBoardEncoder, factorized.
//
// piece_ids in [0,7), color_ids in [0,3), square in [0,64): the per-square
// token LN(W[c] @ piece_table[p] + b[c] + square_table[s]) takes only
// 7*3*64 = 1344 distinct values; special tokens take 2+16+9 = 27. Precompute
// all 1371 layernormed rows (ws table), then the op is a pure gather
// (write-bound: 281 MB out @ ~6.9 TB/s fill-rate ≈ 41 us floor).
//
// R6: EXACT R1 structure (best measured: 67.4 us) with ONE change — gather
// stores are nontemporal, so the 281 MB write stream doesn't evict the
// 1.37 MB table from L2 (theory: L2 churn forces table re-reads from L3/HBM,
// explaining gather ~4.8 TB/s vs fill 6.9 TB/s).
// ---------------------------------------------------------------------------

#define DIM 256
#define NPT 7
#define NCOL 3
#define NROWS_SQ (NPT * NCOL * 64)   // 1344
#define ROW_TURN 1344                // 2 rows
#define ROW_CASTLE 1346              // 16 rows
#define ROW_EP 1362                  // 9 rows
#define NROWS_TOT 1371
#define EPSV 1e-5f

typedef float f32x4 __attribute__((ext_vector_type(4)));

// ---- Kernel A: proj[p*3+c][d] = b[c][d] + sum_k W[c][d][k] * piece_table[p][k]
__global__ void proj_kernel(const float* __restrict__ piece_table,
                            const float* __restrict__ W,
                            const float* __restrict__ bvec,
                            float* __restrict__ proj) {
    int e = blockIdx.x;              // 0..20  (p*3 + c)
    int p = e / NCOL, c = e % NCOL;
    int d = threadIdx.x;             // 0..255 (output element o)
    __shared__ float pt[DIM];
    pt[d] = piece_table[p * DIM + d];
    __syncthreads();
    const float4* w4 = (const float4*)(W + (size_t)c * DIM * DIM + (size_t)d * DIM);
    float acc = bvec[c * DIM + d];
    #pragma unroll 8
    for (int k = 0; k < DIM / 4; ++k) {
        float4 w = w4[k];
        acc += w.x * pt[k * 4 + 0] + w.y * pt[k * 4 + 1]
             + w.z * pt[k * 4 + 2] + w.w * pt[k * 4 + 3];
    }
    proj[e * DIM + d] = acc;
}

// ---- Kernel B: layernorm each of the 1371 distinct rows into `table`.
// One wave (64 lanes) per row; each lane owns 4 consecutive floats.
__global__ void ln_table_kernel(const float* __restrict__ proj,
                                const float* __restrict__ square_table,
                                const float* __restrict__ turn_table,
                                const float* __restrict__ castling_table,
                                const float* __restrict__ ep_table,
                                const float* __restrict__ gamma,
                                const float* __restrict__ beta,
                                float* __restrict__ table) {
    int w = blockIdx.x * 4 + (threadIdx.x >> 6);
    int lane = threadIdx.x & 63;
    if (w >= NROWS_TOT) return;

    float4 x;
    if (w < NROWS_SQ) {
        int p = w / 192;
        int rem = w - p * 192;
        int c = rem >> 6;
        int s = rem & 63;
        float4 a = ((const float4*)(proj + (p * NCOL + c) * DIM))[lane];
        float4 q = ((const float4*)(square_table + s * DIM))[lane];
        x = make_float4(a.x + q.x, a.y + q.y, a.z + q.z, a.w + q.w);
    } else if (w < ROW_CASTLE) {
        x = ((const float4*)(turn_table + (w - ROW_TURN) * DIM))[lane];
    } else if (w < ROW_EP) {
        x = ((const float4*)(castling_table + (w - ROW_CASTLE) * DIM))[lane];
    } else {
        x = ((const float4*)(ep_table + (w - ROW_EP) * DIM))[lane];
    }

    float s = x.x + x.y + x.z + x.w;
    #pragma unroll
    for (int m = 1; m < 64; m <<= 1) s += __shfl_xor(s, m, 64);
    float mu = s * (1.0f / DIM);

    float dx = x.x - mu, dy = x.y - mu, dz = x.z - mu, dw = x.w - mu;
    float v = dx * dx + dy * dy + dz * dz + dw * dw;
    #pragma unroll
    for (int m = 1; m < 64; m <<= 1) v += __shfl_xor(v, m, 64);
    float inv = rsqrtf(v * (1.0f / DIM) + EPSV);

    float4 g = ((const float4*)gamma)[lane];
    float4 bb = ((const float4*)beta)[lane];
    float4 y = make_float4(dx * inv * g.x + bb.x,
                           dy * inv * g.y + bb.y,
                           dz * inv * g.z + bb.z,
                           dw * inv * g.w + bb.w);
    ((float4*)(table + (size_t)w * DIM))[lane] = y;
}

// ---- Kernel C: gather. One wave per output row (b, t); f32x4 row copy with
// nontemporal stores (keep the table L2-resident; stream the output).
__global__ void gather_kernel(const int* __restrict__ piece_ids,
                              const int* __restrict__ color_ids,
                              const int* __restrict__ turn,
                              const int* __restrict__ castling,
                              const int* __restrict__ ep_file,
                              const float* __restrict__ table,
                              float* __restrict__ out,
                              int nrows) {
    int r = blockIdx.x * 4 + (threadIdx.x >> 6);
    if (r >= nrows) return;
    int lane = threadIdx.x & 63;
    int b = r / 67;
    int t = r - b * 67;
    int row;
    if (t == 0) {
        row = ROW_TURN + turn[b];
    } else if (t == 1) {
        row = ROW_CASTLE + castling[b];
    } else if (t == 2) {
        row = ROW_EP + ep_file[b];
    } else {
        int s = t - 3;
        int idx = b * 64 + s;
        row = piece_ids[idx] * (NCOL * 64) + color_ids[idx] * 64 + s;
    }
    f32x4 v = ((const f32x4*)(table + (size_t)row * DIM))[lane];
    __builtin_nontemporal_store(v, (f32x4*)(out + (size_t)r * DIM) + lane);
}

extern "C" void kernel_launch(void* const* d_in, const int* in_sizes, int n_in,
                              void* d_out, int out_size, void* d_ws, size_t ws_size,
                              hipStream_t stream) {
    const int*   piece_ids      = (const int*)d_in[0];
    const int*   color_ids      = (const int*)d_in[1];
    const int*   turn           = (const int*)d_in[2];
    const int*   castling       = (const int*)d_in[3];
    const int*   ep_file        = (const int*)d_in[4];
    const float* piece_table    = (const float*)d_in[5];
    const float* W              = (const float*)d_in[6];
    const float* bvec           = (const float*)d_in[7];
    const float* square_table   = (const float*)d_in[8];
    const float* turn_table     = (const float*)d_in[9];
    const float* castling_table = (const float*)d_in[10];
    const float* ep_table       = (const float*)d_in[11];
    const float* gamma          = (const float*)d_in[12];
    const float* beta           = (const float*)d_in[13];
    float* out = (float*)d_out;

    int B = in_sizes[0] / 64;
    int nrows = B * 67;

    float* proj  = (float*)d_ws;                 // 21 * 256 floats
    float* table = proj + NPT * NCOL * DIM;      // 1371 * 256 floats

    proj_kernel<<<NPT * NCOL, 256, 0, stream>>>(piece_table, W, bvec, proj);
    ln_table_kernel<<<(NROWS_TOT + 3) / 4, 256, 0, stream>>>(
        proj, square_table, turn_table, castling_table, ep_table, gamma, beta, table);
    gather_kernel<<<(nrows + 3) / 4, 256, 0, stream>>>(
        piece_ids, color_ids, turn, castling, ep_file, table, out, nrows);
}